// Round 6
// baseline (171.998 us; speedup 1.0000x reference)
//
#include <hip/hip_runtime.h>
#include <hip/hip_bf16.h>
#include <stdint.h>

#define DEV __device__ __forceinline__

typedef unsigned short u16;
typedef __attribute__((ext_vector_type(8))) short bf16x8;   // 8 bf16 (4 VGPRs) MFMA A/B frag
typedef __attribute__((ext_vector_type(4))) float f32x4;    // MFMA C/D frag

DEV u16 bf(float v) {
  __hip_bfloat16 h = __float2bfloat16(v);
  union { __hip_bfloat16 h; u16 u; } x; x.h = h;
  return x.u;
}

// sigmoid(v/sqrt(512)) = 1/(1+exp2(v * -log2(e)/sqrt(512)))
DEV float sigmoid_s(float v) {
  float e = __builtin_amdgcn_exp2f(v * -0.0637587143f);
  return __builtin_amdgcn_rcpf(1.0f + e);
}

DEV void gld_lds(const u16* g, u16* l) {
  __builtin_amdgcn_global_load_lds(
      (const __attribute__((address_space(1))) uint32_t*)g,
      (__attribute__((address_space(3))) uint32_t*)l, 16, 0, 0);
}

// ---------------- f32 -> bf16 conversion (x, Wq, Wv) ----------------
__global__ void conv_kernel(const float* __restrict__ x,
                            const float* __restrict__ Wq,
                            const float* __restrict__ Wv,
                            u16* __restrict__ xb,
                            u16* __restrict__ wqb,
                            u16* __restrict__ wvb) {
  const int NX4 = (16384 * 512) / 4;
  const int NW4 = (512 * 512) / 4;
  int i = blockIdx.x * blockDim.x + threadIdx.x;
  const float4* src; u16* dst; int off;
  if (i < NX4)            { src = (const float4*)x;  dst = xb;  off = i; }
  else if (i < NX4 + NW4) { src = (const float4*)Wq; dst = wqb; off = i - NX4; }
  else                    { src = (const float4*)Wv; dst = wvb; off = i - NX4 - NW4; }
  float4 f = src[off];
  ushort4 o = make_ushort4(bf(f.x), bf(f.y), bf(f.z), bf(f.w));
  ((ushort4*)dst)[off] = o;
}

// ---------------- generic BMxBN (BK=64) NT GEMM, 2-phase dbuf, bf16, MFMA ----
// C[m][n] = sum_k A[m][k] * B[n][k]  (both row-major with K inner = NT)
// T1 XCD swizzle; T2 LDS XOR swizzle (both-sides, rule #21);
// T3/T4 minimum 2-phase: prefetch kt+1 into other buffer, counted vmcnt(CPW)
// before raw s_barrier (no full drain), vmcnt(0) only on the last step.
// EPI: 0 = +bias[col] -> bf16 | 1 = +bias[row] -> bf16 | 3 = f32 out
template <int EPI, int BM, int BN, int NBN, int NBM>
__global__ __launch_bounds__(256, 2)
void gemm_nt(const u16* __restrict__ A, int lda, long sAz,
             const u16* __restrict__ B, int ldb, long sBz,
             void* __restrict__ Cv, int ldc, long sCz,
             const float* __restrict__ bias, int K) {
  constexpr int BK   = 64;
  constexpr int MREP = BM / 32;
  constexpr int NREP = BN / 32;
  constexpr int CPW  = (BM + BN) / 8 / 4;   // 1KB chunks per wave per K-step
  constexpr int TILE = (BM + BN) * BK;      // u16 per buffer
  __shared__ u16 lds[2 * TILE];

  const int tid  = threadIdx.x;
  const int lane = tid & 63;
  const int w    = tid >> 6;        // wave 0..3
  const int wr   = w >> 1, wc = w & 1;

  const int nwg = (int)gridDim.x;   // divisible by 8
  const int id  = blockIdx.x;
  const int swz = (id & 7) * (nwg >> 3) + (id >> 3);
  const int bn  = swz % NBN;
  const int t0  = swz / NBN;
  const int bm  = t0 % NBM;
  const int z   = t0 / NBM;

  A += (long)z * sAz;
  B += (long)z * sBz;

  const int lrow = lane & 15;           // frag row (A) / col (B)
  const int rx   = lane & 7;            // read-side swizzle key (lrow & 7)

  const int srow = lane >> 3;                    // 0..7 within 1KB chunk
  const int scol = ((lane & 7) ^ srow) << 3;     // pre-swizzled source slot

  const u16* srcs[CPW];
#pragma unroll
  for (int c = 0; c < CPW; ++c) {
    int row = (w * CPW + c) * 8 + srow;          // row within [A-tile | B-tile]
    srcs[c] = (row < BM)
        ? A + (long)(bm * BM + row) * lda + scol
        : B + (long)(bn * BN + (row - BM)) * ldb + scol;
  }

  f32x4 acc[MREP][NREP] = {};

  const int nk = K / BK;
#pragma unroll
  for (int c = 0; c < CPW; ++c)
    gld_lds(srcs[c], &lds[(w * CPW + c) * 512]);

  int p = 0;
  for (int kt = 0; kt < nk; ++kt) {
    if (kt + 1 < nk) {
#pragma unroll
      for (int c = 0; c < CPW; ++c)
        gld_lds(srcs[c] + (kt + 1) * BK, &lds[(p ^ 1) * TILE + (w * CPW + c) * 512]);
      asm volatile("s_waitcnt vmcnt(%0)" :: "i"(CPW) : "memory");
    } else {
      asm volatile("s_waitcnt vmcnt(0)" ::: "memory");
    }
    __builtin_amdgcn_s_barrier();
    asm volatile("" ::: "memory");

    const u16* Alds = &lds[p * TILE];
    const u16* Blds = &lds[p * TILE + BM * BK];
#pragma unroll
    for (int ks = 0; ks < 2; ++ks) {
      const int sl = ((ks * 4 + (lane >> 4)) ^ rx) << 3;
      bf16x8 af[MREP], bfr[NREP];
#pragma unroll
      for (int t = 0; t < MREP; ++t)
        af[t]  = *(const bf16x8*)&Alds[(wr * (BM / 2) + t * 16 + lrow) * BK + sl];
#pragma unroll
      for (int t = 0; t < NREP; ++t)
        bfr[t] = *(const bf16x8*)&Blds[(wc * (BN / 2) + t * 16 + lrow) * BK + sl];
#pragma unroll
      for (int mt = 0; mt < MREP; ++mt)
#pragma unroll
        for (int nt = 0; nt < NREP; ++nt)
          acc[mt][nt] = __builtin_amdgcn_mfma_f32_16x16x32_bf16(af[mt], bfr[nt], acc[mt][nt], 0, 0, 0);
    }

    asm volatile("" ::: "memory");
    __builtin_amdgcn_s_barrier();
    p ^= 1;
  }

  // epilogue: C/D layout col = lane&15, row = (lane>>4)*4 + r  [verified m89/m91]
  const int row0 = bm * BM + wr * (BM / 2);
  const int col0 = bn * BN + wc * (BN / 2);
  const int rsub = (lane >> 4) << 2;

  if (EPI == 3) {
    float* C = (float*)Cv + (long)z * sCz;
#pragma unroll
    for (int mt = 0; mt < MREP; ++mt)
#pragma unroll
      for (int nt = 0; nt < NREP; ++nt)
#pragma unroll
        for (int r = 0; r < 4; ++r)
          C[(long)(row0 + mt * 16 + rsub + r) * ldc + col0 + nt * 16 + lrow] = acc[mt][nt][r];
  } else {
    u16* C = (u16*)Cv + (long)z * sCz;
#pragma unroll
    for (int mt = 0; mt < MREP; ++mt)
#pragma unroll
      for (int nt = 0; nt < NREP; ++nt)
#pragma unroll
        for (int r = 0; r < 4; ++r) {
          int row = row0 + mt * 16 + rsub + r;
          int col = col0 + nt * 16 + lrow;
          float v = acc[mt][nt][r];
          if (EPI == 0) v += bias[col];
          if (EPI == 1) v += bias[row];
          C[(long)row * ldc + col] = bf(v);
        }
  }
}

// ---------------- symmetric sigmoid(QQ^T) GEMM: only bn>=bm tiles ----------------
// 2-phase dbuf K-loop; off-diagonal blocks store normal + transposed tile,
// both via padded-LDS bounce (overlays staging buf0 after final barrier).
template <int NB>   // tiles per dim; BM=BN=128; TRI = NB*(NB+1)/2
__global__ __launch_bounds__(256, 2)
void gemm_sym_sig(const u16* __restrict__ Q, int ldq, long sQz,
                  u16* __restrict__ P, int ldp, long sPz, int K) {
  constexpr int TRI  = NB * (NB + 1) / 2;
  constexpr int TILE = 256 * 64;
  constexpr int LSTR = 136;                  // bounce row stride (u16)
  __shared__ u16 lds[2 * TILE];

  const int tid  = threadIdx.x;
  const int lane = tid & 63;
  const int w    = tid >> 6;
  const int wr   = w >> 1, wc = w & 1;

  const int nwg = (int)gridDim.x;
  const int id  = blockIdx.x;
  const int swz = (id & 7) * (nwg >> 3) + (id >> 3);
  const int z   = swz / TRI;
  int rem = swz % TRI;
  int bm = 0;
  while (rem >= NB - bm) { rem -= NB - bm; ++bm; }
  const int bn = bm + rem;

  const u16* Qz = Q + (long)z * sQz;

  const int lrow = lane & 15;
  const int rx   = lane & 7;
  const int srow = lane >> 3;
  const int scol = ((lane & 7) ^ srow) << 3;

  const u16* srcs[8];
#pragma unroll
  for (int c = 0; c < 8; ++c) {
    int row = (w * 8 + c) * 8 + srow;
    srcs[c] = (row < 128)
        ? Qz + (long)(bm * 128 + row) * ldq + scol
        : Qz + (long)(bn * 128 + (row - 128)) * ldq + scol;
  }

  f32x4 acc[4][4] = {};

  const int nk = K >> 6;
#pragma unroll
  for (int c = 0; c < 8; ++c)
    gld_lds(srcs[c], &lds[(w * 8 + c) * 512]);

  int p = 0;
  for (int kt = 0; kt < nk; ++kt) {
    if (kt + 1 < nk) {
#pragma unroll
      for (int c = 0; c < 8; ++c)
        gld_lds(srcs[c] + (kt + 1) * 64, &lds[(p ^ 1) * TILE + (w * 8 + c) * 512]);
      asm volatile("s_waitcnt vmcnt(8)" ::: "memory");
    } else {
      asm volatile("s_waitcnt vmcnt(0)" ::: "memory");
    }
    __builtin_amdgcn_s_barrier();
    asm volatile("" ::: "memory");

    const u16* Alds = &lds[p * TILE];
    const u16* Blds = &lds[p * TILE + 128 * 64];
#pragma unroll
    for (int ks = 0; ks < 2; ++ks) {
      const int sl = ((ks * 4 + (lane >> 4)) ^ rx) << 3;
      bf16x8 af[4], bfr[4];
#pragma unroll
      for (int t = 0; t < 4; ++t) {
        af[t]  = *(const bf16x8*)&Alds[(wr * 64 + t * 16 + lrow) * 64 + sl];
        bfr[t] = *(const bf16x8*)&Blds[(wc * 64 + t * 16 + lrow) * 64 + sl];
      }
#pragma unroll
      for (int mt = 0; mt < 4; ++mt)
#pragma unroll
        for (int nt = 0; nt < 4; ++nt)
          acc[mt][nt] = __builtin_amdgcn_mfma_f32_16x16x32_bf16(af[mt], bfr[nt], acc[mt][nt], 0, 0, 0);
    }

    asm volatile("" ::: "memory");
    __builtin_amdgcn_s_barrier();
    p ^= 1;
  }

  u16* Pz = P + (long)z * sPz;
  const int rsub = (lane >> 4) << 2;
  const bool offdiag = (bn != bm);

  // sigmoid all 64 outputs once
  u16 sb[4][4][4];
#pragma unroll
  for (int mt = 0; mt < 4; ++mt)
#pragma unroll
    for (int nt = 0; nt < 4; ++nt)
#pragma unroll
      for (int r = 0; r < 4; ++r)
        sb[mt][nt][r] = bf(sigmoid_s(acc[mt][nt][r]));

  const int rl = wr * 64 + rsub;   // local row base (+mt*16, +r)
  const int cl = wc * 64 + lrow;   // local col base (+nt*16)
  const int coloff = (lane & 15) * 8;

  // pass 1: normal orientation bounce -> coalesced 256B row stores
#pragma unroll
  for (int mt = 0; mt < 4; ++mt)
#pragma unroll
    for (int nt = 0; nt < 4; ++nt)
#pragma unroll
      for (int r = 0; r < 4; ++r)
        lds[(rl + mt * 16 + r) * LSTR + cl + nt * 16] = sb[mt][nt][r];
  __syncthreads();
#pragma unroll
  for (int j = 0; j < 8; ++j) {
    int row = j * 16 + w * 4 + (lane >> 4);
    bf16x8 v = *(const bf16x8*)&lds[row * LSTR + coloff];
    *(bf16x8*)&Pz[(long)(bm * 128 + row) * ldp + bn * 128 + coloff] = v;
  }

  if (offdiag) {
    __syncthreads();   // WAR: pass-1 reads done before overwrite
    // pass 2: transposed orientation; frag's 4 rows = 4 consecutive u16 -> uint2
#pragma unroll
    for (int mt = 0; mt < 4; ++mt)
#pragma unroll
      for (int nt = 0; nt < 4; ++nt) {
        uint2 pk;
        pk.x = (uint32_t)sb[mt][nt][0] | ((uint32_t)sb[mt][nt][1] << 16);
        pk.y = (uint32_t)sb[mt][nt][2] | ((uint32_t)sb[mt][nt][3] << 16);
        *(uint2*)&lds[(cl + nt * 16) * LSTR + rl + mt * 16] = pk;
      }
    __syncthreads();
#pragma unroll
    for (int j = 0; j < 8; ++j) {
      int row = j * 16 + w * 4 + (lane >> 4);
      bf16x8 v = *(const bf16x8*)&lds[row * LSTR + coloff];
      *(bf16x8*)&Pz[(long)(bn * 128 + row) * ldp + bm * 128 + coloff] = v;
    }
  }
}

// ---------------- launch ----------------
extern "C" void kernel_launch(void* const* d_in, const int* in_sizes, int n_in,
                              void* d_out, int out_size, void* d_ws, size_t ws_size,
                              hipStream_t stream) {
  const float* x  = (const float*)d_in[0];   // [4,4096,512]
  const float* Wq = (const float*)d_in[1];   // [512,512]
  const float* bq = (const float*)d_in[2];   // [512]
  const float* Wv = (const float*)d_in[3];   // [512,512]
  const float* bv = (const float*)d_in[4];   // [512]
  float* out = (float*)d_out;                // [4,4096,512] f32

  // workspace carve (all bf16)
  u16* xb  = (u16*)d_ws;                       // [16384][512]
  u16* qb  = xb  + (size_t)16384 * 512;        // [16384][512]
  u16* vT  = qb  + (size_t)16384 * 512;        // [512][16384]  (v transposed; batch col slices)
  u16* wqb = vT  + (size_t)512 * 16384;        // [512][512]
  u16* wvb = wqb + (size_t)512 * 512;          // [512][512]
  u16* P   = wvb + (size_t)512 * 512;          // [4 or 2][4096][4096] bf16

  const size_t base_elems = (size_t)16384 * 512 * 3 + (size_t)512 * 512 * 2;
  const size_t need_all4  = (base_elems + (size_t)4 * 4096 * 4096) * sizeof(u16);
  const bool all4 = ws_size >= need_all4;

  conv_kernel<<<8704, 256, 0, stream>>>(x, Wq, Wv, xb, wqb, wvb);

  // q[n][e] = sum_d xb[n][d]*Wq[e][d] + bq[e]   (bias per col)
  gemm_nt<0, 128, 128, 4, 128><<<512, 256, 0, stream>>>(xb, 512, 0, wqb, 512, 0,
                                                        qb, 512, 0, bq, 512);
  // vT[e][n] = sum_d Wv[e][d]*xb[n][d] + bv[e]  (bias per row)
  gemm_nt<1, 128, 128, 128, 4><<<512, 256, 0, stream>>>(wvb, 512, 0, xb, 512, 0,
                                                        vT, 16384, 0, bv, 512);

  if (all4) {
    // P = sigmoid(q q^T / sqrt(512)), symmetric: 528 tiles/batch, both halves stored
    gemm_sym_sig<32><<<4 * 528, 256, 0, stream>>>(qb, 512, (long)4096 * 512,
                                                  P, 4096, (long)4096 * 4096, 512);
    // O[n][d] = sum_m P[n][m] * v[m][d]; 128x128 tile, BK=64 (conflict-free swizzle)
    gemm_nt<3, 128, 128, 4, 32><<<512, 256, 0, stream>>>(
        P, 4096, (long)4096 * 4096, vT, 16384, (long)4096,
        out, 512, (long)4096 * 512, nullptr, 4096);
  } else {
    for (int p = 0; p < 2; ++p) {
      const u16* qbp = qb + (size_t)p * 2 * 4096 * 512;
      gemm_sym_sig<32><<<2 * 528, 256, 0, stream>>>(qbp, 512, (long)4096 * 512,
                                                    P, 4096, (long)4096 * 4096, 512);
      gemm_nt<3, 64, 128, 4, 64><<<512, 256, 0, stream>>>(
          P, 4096, (long)4096 * 4096, vT + (size_t)p * 2 * 4096, 16384, (long)4096,
          out + (size_t)p * 2 * 4096 * 512, 512, (long)4096 * 512, nullptr, 4096);
    }
  }
}

// Round 7
// 164.370 us; speedup vs baseline: 1.0464x; 1.0464x over previous
//
#include <hip/hip_runtime.h>
#include <hip/hip_bf16.h>
#include <stdint.h>

#define DEV __device__ __forceinline__

typedef unsigned short u16;
typedef __attribute__((ext_vector_type(8))) short bf16x8;   // 8 bf16 (4 VGPRs) MFMA A/B frag
typedef __attribute__((ext_vector_type(4))) float f32x4;    // MFMA C/D frag

DEV u16 bf(float v) {
  __hip_bfloat16 h = __float2bfloat16(v);
  union { __hip_bfloat16 h; u16 u; } x; x.h = h;
  return x.u;
}

// sigmoid(v/sqrt(512)) = 1/(1+exp2(v * -log2(e)/sqrt(512)))
DEV float sigmoid_s(float v) {
  float e = __builtin_amdgcn_exp2f(v * -0.0637587143f);
  return __builtin_amdgcn_rcpf(1.0f + e);
}

DEV void gld_lds(const u16* g, u16* l) {
  __builtin_amdgcn_global_load_lds(
      (const __attribute__((address_space(1))) uint32_t*)g,
      (__attribute__((address_space(3))) uint32_t*)l, 16, 0, 0);
}

// ---------------- f32 -> bf16 conversion (x, Wq, Wv) ----------------
__global__ void conv_kernel(const float* __restrict__ x,
                            const float* __restrict__ Wq,
                            const float* __restrict__ Wv,
                            u16* __restrict__ xb,
                            u16* __restrict__ wqb,
                            u16* __restrict__ wvb) {
  const int NX4 = (16384 * 512) / 4;
  const int NW4 = (512 * 512) / 4;
  int i = blockIdx.x * blockDim.x + threadIdx.x;
  const float4* src; u16* dst; int off;
  if (i < NX4)            { src = (const float4*)x;  dst = xb;  off = i; }
  else if (i < NX4 + NW4) { src = (const float4*)Wq; dst = wqb; off = i - NX4; }
  else                    { src = (const float4*)Wv; dst = wvb; off = i - NX4 - NW4; }
  float4 f = src[off];
  ushort4 o = make_ushort4(bf(f.x), bf(f.y), bf(f.z), bf(f.w));
  ((ushort4*)dst)[off] = o;
}

// ---------------- generic BMxBN (BK=64) NT GEMM, 2-phase dbuf, bf16, MFMA ----
// C[m][n] = sum_k A[m][k] * B[n][k]  (both row-major with K inner = NT)
// NW waves arranged 2 x (NW/2); wave tile = (BM/2) x (BN/(NW/2)).
// T1 XCD swizzle; T2 LDS XOR swizzle (both-sides, rule #21);
// 2-phase: prefetch kt+1 into other buffer, counted vmcnt(CPW) before raw
// s_barrier (no full drain); vmcnt(0) only on the last K-step.
// EPI: 0 = +bias[col] -> bf16 | 1 = +bias[row] -> bf16 | 3 = f32 out
template <int EPI, int BM, int BN, int NW, int NBN, int NBM>
__global__ __launch_bounds__(NW * 64, 2)
void gemm_nt(const u16* __restrict__ A, int lda, long sAz,
             const u16* __restrict__ B, int ldb, long sBz,
             void* __restrict__ Cv, int ldc, long sCz,
             const float* __restrict__ bias, int K) {
  constexpr int BK   = 64;
  constexpr int WC   = NW / 2;               // wave-cols
  constexpr int MREP = BM / 32;              // frags per wave, M (wave rows = BM/2)
  constexpr int NREP = BN / (16 * WC);       // frags per wave, N
  constexpr int CPW  = (BM + BN) / (8 * NW); // 1KB chunks per wave per K-step
  constexpr int TILE = (BM + BN) * BK;       // u16 per buffer
  __shared__ u16 lds[2 * TILE];

  const int tid  = threadIdx.x;
  const int lane = tid & 63;
  const int w    = tid >> 6;        // wave 0..NW-1
  const int wr   = w / WC, wc = w % WC;

  const int nwg = (int)gridDim.x;   // divisible by 8
  const int id  = blockIdx.x;
  const int swz = (id & 7) * (nwg >> 3) + (id >> 3);
  const int bn  = swz % NBN;
  const int t0  = swz / NBN;
  const int bm  = t0 % NBM;
  const int z   = t0 / NBM;

  A += (long)z * sAz;
  B += (long)z * sBz;

  const int lrow = lane & 15;           // frag row (A) / col (B)
  const int rx   = lane & 7;            // read-side swizzle key (lrow & 7)

  const int srow = lane >> 3;                    // 0..7 within 1KB chunk
  const int scol = ((lane & 7) ^ srow) << 3;     // pre-swizzled source slot

  const u16* srcs[CPW];
#pragma unroll
  for (int c = 0; c < CPW; ++c) {
    int row = (w * CPW + c) * 8 + srow;          // row within [A-tile | B-tile]
    srcs[c] = (row < BM)
        ? A + (long)(bm * BM + row) * lda + scol
        : B + (long)(bn * BN + (row - BM)) * ldb + scol;
  }

  f32x4 acc[MREP][NREP] = {};

  const int nk = K / BK;
#pragma unroll
  for (int c = 0; c < CPW; ++c)
    gld_lds(srcs[c], &lds[(w * CPW + c) * 512]);

  int p = 0;
  for (int kt = 0; kt < nk; ++kt) {
    if (kt + 1 < nk) {
#pragma unroll
      for (int c = 0; c < CPW; ++c)
        gld_lds(srcs[c] + (kt + 1) * BK, &lds[(p ^ 1) * TILE + (w * CPW + c) * 512]);
      asm volatile("s_waitcnt vmcnt(%0)" :: "i"(CPW) : "memory");
    } else {
      asm volatile("s_waitcnt vmcnt(0)" ::: "memory");
    }
    __builtin_amdgcn_s_barrier();
    asm volatile("" ::: "memory");

    const u16* Alds = &lds[p * TILE];
    const u16* Blds = &lds[p * TILE + BM * BK];
#pragma unroll
    for (int ks = 0; ks < 2; ++ks) {
      const int sl = ((ks * 4 + (lane >> 4)) ^ rx) << 3;
      bf16x8 af[MREP], bfr[NREP];
#pragma unroll
      for (int t = 0; t < MREP; ++t)
        af[t]  = *(const bf16x8*)&Alds[(wr * (BM / 2) + t * 16 + lrow) * BK + sl];
#pragma unroll
      for (int t = 0; t < NREP; ++t)
        bfr[t] = *(const bf16x8*)&Blds[(wc * (BN / WC) + t * 16 + lrow) * BK + sl];
#pragma unroll
      for (int mt = 0; mt < MREP; ++mt)
#pragma unroll
        for (int nt = 0; nt < NREP; ++nt)
          acc[mt][nt] = __builtin_amdgcn_mfma_f32_16x16x32_bf16(af[mt], bfr[nt], acc[mt][nt], 0, 0, 0);
    }

    asm volatile("" ::: "memory");
    __builtin_amdgcn_s_barrier();
    p ^= 1;
  }

  // epilogue: C/D layout col = lane&15, row = (lane>>4)*4 + r  [verified m89/m91]
  const int row0 = bm * BM + wr * (BM / 2);
  const int col0 = bn * BN + wc * (BN / WC);
  const int rsub = (lane >> 4) << 2;

  if (EPI == 3) {
    float* C = (float*)Cv + (long)z * sCz;
#pragma unroll
    for (int mt = 0; mt < MREP; ++mt)
#pragma unroll
      for (int nt = 0; nt < NREP; ++nt)
#pragma unroll
        for (int r = 0; r < 4; ++r)
          C[(long)(row0 + mt * 16 + rsub + r) * ldc + col0 + nt * 16 + lrow] = acc[mt][nt][r];
  } else {
    u16* C = (u16*)Cv + (long)z * sCz;
#pragma unroll
    for (int mt = 0; mt < MREP; ++mt)
#pragma unroll
      for (int nt = 0; nt < NREP; ++nt)
#pragma unroll
        for (int r = 0; r < 4; ++r) {
          int row = row0 + mt * 16 + rsub + r;
          int col = col0 + nt * 16 + lrow;
          float v = acc[mt][nt][r];
          if (EPI == 0) v += bias[col];
          if (EPI == 1) v += bias[row];
          C[(long)row * ldc + col] = bf(v);
        }
  }
}

// ---------------- symmetric sigmoid(QQ^T) GEMM: only bn>=bm tiles ----------------
// (round-5 form: single-buffered staging, 34 KB LDS -> 4 blocks/CU.)
// Off-diagonal blocks store normal + transposed tile; both via padded-LDS
// bounce (overlays staging) so all global stores are 256B-dense.
template <int NB>   // tiles per dim; BM=BN=128; TRI = NB*(NB+1)/2
__global__ __launch_bounds__(256, 2)
void gemm_sym_sig(const u16* __restrict__ Q, int ldq, long sQz,
                  u16* __restrict__ P, int ldp, long sPz, int K) {
  constexpr int TRI = NB * (NB + 1) / 2;
  constexpr int LSTR = 136;                  // u16 row stride: 16B-aligned, bank-spread
  __shared__ u16 lds[128 * LSTR];            // staging (256*64=16384) | bounce (128*136)

  const int tid  = threadIdx.x;
  const int lane = tid & 63;
  const int w    = tid >> 6;
  const int wr   = w >> 1, wc = w & 1;

  const int nwg = (int)gridDim.x;
  const int id  = blockIdx.x;
  const int swz = (id & 7) * (nwg >> 3) + (id >> 3);
  const int z   = swz / TRI;
  int rem = swz % TRI;
  int bm = 0;
  while (rem >= NB - bm) { rem -= NB - bm; ++bm; }
  const int bn = bm + rem;

  const u16* Qz = Q + (long)z * sQz;

  const int lrow = lane & 15;
  const int rx   = lane & 7;
  const int srow = lane >> 3;
  const int scol = ((lane & 7) ^ srow) << 3;

  const u16* srcs[8];
#pragma unroll
  for (int c = 0; c < 8; ++c) {
    int row = (w * 8 + c) * 8 + srow;
    srcs[c] = (row < 128)
        ? Qz + (long)(bm * 128 + row) * ldq + scol
        : Qz + (long)(bn * 128 + (row - 128)) * ldq + scol;
  }

  const u16* Alds = lds;
  const u16* Blds = lds + 128 * 64;

  f32x4 acc[4][4] = {};

  const int nk = K >> 6;
  for (int kt = 0; kt < nk; ++kt) {
#pragma unroll
    for (int c = 0; c < 8; ++c)
      gld_lds(srcs[c] + kt * 64, &lds[(w * 8 + c) * 512]);
    __syncthreads();

#pragma unroll
    for (int ks = 0; ks < 2; ++ks) {
      const int sl = ((ks * 4 + (lane >> 4)) ^ rx) << 3;
      bf16x8 af[4], bfr[4];
#pragma unroll
      for (int t = 0; t < 4; ++t) {
        af[t]  = *(const bf16x8*)&Alds[(wr * 64 + t * 16 + lrow) * 64 + sl];
        bfr[t] = *(const bf16x8*)&Blds[(wc * 64 + t * 16 + lrow) * 64 + sl];
      }
#pragma unroll
      for (int mt = 0; mt < 4; ++mt)
#pragma unroll
        for (int nt = 0; nt < 4; ++nt)
          acc[mt][nt] = __builtin_amdgcn_mfma_f32_16x16x32_bf16(af[mt], bfr[nt], acc[mt][nt], 0, 0, 0);
    }
    __syncthreads();
  }

  u16* Pz = P + (long)z * sPz;
  const int rsub = (lane >> 4) << 2;
  const bool offdiag = (bn != bm);

  // sigmoid all 64 outputs once
  u16 sb[4][4][4];
#pragma unroll
  for (int mt = 0; mt < 4; ++mt)
#pragma unroll
    for (int nt = 0; nt < 4; ++nt)
#pragma unroll
      for (int r = 0; r < 4; ++r)
        sb[mt][nt][r] = bf(sigmoid_s(acc[mt][nt][r]));

  const int rl = wr * 64 + rsub;   // local row base (+mt*16, +r)
  const int cl = wc * 64 + lrow;   // local col base (+nt*16)
  const int coloff = (lane & 15) * 8;

  // pass 1: normal orientation bounce -> coalesced 256B row stores
#pragma unroll
  for (int mt = 0; mt < 4; ++mt)
#pragma unroll
    for (int nt = 0; nt < 4; ++nt)
#pragma unroll
      for (int r = 0; r < 4; ++r)
        lds[(rl + mt * 16 + r) * LSTR + cl + nt * 16] = sb[mt][nt][r];
  __syncthreads();
#pragma unroll
  for (int j = 0; j < 8; ++j) {
    int row = j * 16 + w * 4 + (lane >> 4);
    bf16x8 v = *(const bf16x8*)&lds[row * LSTR + coloff];
    *(bf16x8*)&Pz[(long)(bm * 128 + row) * ldp + bn * 128 + coloff] = v;
  }

  if (offdiag) {
    __syncthreads();   // WAR: pass-1 reads done before overwrite
    // pass 2: transposed orientation; frag's 4 rows = 4 consecutive u16 -> uint2
#pragma unroll
    for (int mt = 0; mt < 4; ++mt)
#pragma unroll
      for (int nt = 0; nt < 4; ++nt) {
        uint2 pk;
        pk.x = (uint32_t)sb[mt][nt][0] | ((uint32_t)sb[mt][nt][1] << 16);
        pk.y = (uint32_t)sb[mt][nt][2] | ((uint32_t)sb[mt][nt][3] << 16);
        *(uint2*)&lds[(cl + nt * 16) * LSTR + rl + mt * 16] = pk;
      }
    __syncthreads();
#pragma unroll
    for (int j = 0; j < 8; ++j) {
      int row = j * 16 + w * 4 + (lane >> 4);
      bf16x8 v = *(const bf16x8*)&lds[row * LSTR + coloff];
      *(bf16x8*)&Pz[(long)(bn * 128 + row) * ldp + bm * 128 + coloff] = v;
    }
  }
}

// ---------------- launch ----------------
extern "C" void kernel_launch(void* const* d_in, const int* in_sizes, int n_in,
                              void* d_out, int out_size, void* d_ws, size_t ws_size,
                              hipStream_t stream) {
  const float* x  = (const float*)d_in[0];   // [4,4096,512]
  const float* Wq = (const float*)d_in[1];   // [512,512]
  const float* bq = (const float*)d_in[2];   // [512]
  const float* Wv = (const float*)d_in[3];   // [512,512]
  const float* bv = (const float*)d_in[4];   // [512]
  float* out = (float*)d_out;                // [4,4096,512] f32

  // workspace carve (all bf16)
  u16* xb  = (u16*)d_ws;                       // [16384][512]
  u16* qb  = xb  + (size_t)16384 * 512;        // [16384][512]
  u16* vT  = qb  + (size_t)16384 * 512;        // [512][16384]  (v transposed; batch col slices)
  u16* wqb = vT  + (size_t)512 * 16384;        // [512][512]
  u16* wvb = wqb + (size_t)512 * 512;          // [512][512]
  u16* P   = wvb + (size_t)512 * 512;          // [4 or 2][4096][4096] bf16

  const size_t base_elems = (size_t)16384 * 512 * 3 + (size_t)512 * 512 * 2;
  const size_t need_all4  = (base_elems + (size_t)4 * 4096 * 4096) * sizeof(u16);
  const bool all4 = ws_size >= need_all4;

  conv_kernel<<<8704, 256, 0, stream>>>(x, Wq, Wv, xb, wqb, wvb);

  // q[n][e] = sum_d xb[n][d]*Wq[e][d] + bq[e]   (bias per col)
  gemm_nt<0, 128, 128, 4, 4, 128><<<512, 256, 0, stream>>>(xb, 512, 0, wqb, 512, 0,
                                                           qb, 512, 0, bq, 512);
  // vT[e][n] = sum_d Wv[e][d]*xb[n][d] + bv[e]  (bias per row)
  gemm_nt<1, 128, 128, 4, 128, 4><<<512, 256, 0, stream>>>(wvb, 512, 0, xb, 512, 0,
                                                           vT, 16384, 0, bv, 512);

  if (all4) {
    // P = sigmoid(q q^T / sqrt(512)), symmetric: 528 tiles/batch, both halves stored
    gemm_sym_sig<32><<<4 * 528, 256, 0, stream>>>(qb, 512, (long)4096 * 512,
                                                  P, 4096, (long)4096 * 4096, 512);
    // O[n][d] = sum_m P[n][m] * v[m][d]; 128x128 tile, 8 waves (16 waves/CU)
    gemm_nt<3, 128, 128, 8, 4, 32><<<512, 512, 0, stream>>>(
        P, 4096, (long)4096 * 4096, vT, 16384, (long)4096,
        out, 512, (long)4096 * 512, nullptr, 4096);
  } else {
    for (int p = 0; p < 2; ++p) {
      const u16* qbp = qb + (size_t)p * 2 * 4096 * 512;
      gemm_sym_sig<32><<<2 * 528, 256, 0, stream>>>(qbp, 512, (long)4096 * 512,
                                                    P, 4096, (long)4096 * 4096, 512);
      gemm_nt<3, 64, 128, 4, 4, 64><<<512, 256, 0, stream>>>(
          P, 4096, (long)4096 * 4096, vT + (size_t)p * 2 * 4096, 16384, (long)4096,
          out + (size_t)p * 2 * 4096 * 512, 512, (long)4096 * 512, nullptr, 4096);
    }
  }
}

// Round 8
// 143.034 us; speedup vs baseline: 1.2025x; 1.1492x over previous
//
#include <hip/hip_runtime.h>
#include <hip/hip_bf16.h>
#include <stdint.h>

#define DEV __device__ __forceinline__

typedef unsigned short u16;
typedef unsigned char u8;
typedef __attribute__((ext_vector_type(8))) short bf16x8;        // 8 bf16 MFMA A/B frag
typedef __attribute__((ext_vector_type(8))) unsigned short u16x8;
typedef __attribute__((ext_vector_type(4))) float f32x4;         // MFMA C/D frag
typedef __attribute__((ext_vector_type(4))) int i32x4;           // i8 MFMA frag / acc

DEV u16 bf(float v) {
  __hip_bfloat16 h = __float2bfloat16(v);
  union { __hip_bfloat16 h; u16 u; } x; x.h = h;
  return x.u;
}

// sigmoid(v/sqrt(512)) = 1/(1+exp2(v * -log2(e)/sqrt(512)))
DEV float sigmoid_s(float v) {
  float e = __builtin_amdgcn_exp2f(v * -0.0637587143f);
  return __builtin_amdgcn_rcpf(1.0f + e);
}

DEV void gld_lds(const void* g, void* l) {
  __builtin_amdgcn_global_load_lds(
      (const __attribute__((address_space(1))) uint32_t*)g,
      (__attribute__((address_space(3))) uint32_t*)l, 16, 0, 0);
}

// ---------------- f32 -> bf16 conversion (x, Wq, Wv) ----------------
__global__ void conv_kernel(const float* __restrict__ x,
                            const float* __restrict__ Wq,
                            const float* __restrict__ Wv,
                            u16* __restrict__ xb,
                            u16* __restrict__ wqb,
                            u16* __restrict__ wvb) {
  const int NX4 = (16384 * 512) / 4;
  const int NW4 = (512 * 512) / 4;
  int i = blockIdx.x * blockDim.x + threadIdx.x;
  const float4* src; u16* dst; int off;
  if (i < NX4)            { src = (const float4*)x;  dst = xb;  off = i; }
  else if (i < NX4 + NW4) { src = (const float4*)Wq; dst = wqb; off = i - NX4; }
  else                    { src = (const float4*)Wv; dst = wvb; off = i - NX4 - NW4; }
  float4 f = src[off];
  ushort4 o = make_ushort4(bf(f.x), bf(f.y), bf(f.z), bf(f.w));
  ((ushort4*)dst)[off] = o;
}

// ---------------- generic BMxBN (BK=64) NT GEMM, 2-phase dbuf, bf16 in ------
// C[m][n] = sum_k A[m][k] * B[n][k]. T1 XCD swizzle; T2 LDS XOR swizzle.
// EPI: 0 = +bias[col] -> bf16 | 4 = +bias[row] -> i8 quant (scale 127/4)
template <int EPI, int BM, int BN, int NW, int NBN, int NBM>
__global__ __launch_bounds__(NW * 64, 2)
void gemm_nt(const u16* __restrict__ A, int lda, long sAz,
             const u16* __restrict__ B, int ldb, long sBz,
             void* __restrict__ Cv, int ldc, long sCz,
             const float* __restrict__ bias, int K) {
  constexpr int BK   = 64;
  constexpr int WC   = NW / 2;
  constexpr int MREP = BM / 32;
  constexpr int NREP = BN / (16 * WC);
  constexpr int CPW  = (BM + BN) / (8 * NW);
  constexpr int TILE = (BM + BN) * BK;
  __shared__ u16 lds[2 * TILE];

  const int tid  = threadIdx.x;
  const int lane = tid & 63;
  const int w    = tid >> 6;
  const int wr   = w / WC, wc = w % WC;

  const int nwg = (int)gridDim.x;
  const int id  = blockIdx.x;
  const int swz = (id & 7) * (nwg >> 3) + (id >> 3);
  const int bn  = swz % NBN;
  const int t0  = swz / NBN;
  const int bm  = t0 % NBM;
  const int z   = t0 / NBM;

  A += (long)z * sAz;
  B += (long)z * sBz;

  const int lrow = lane & 15;
  const int rx   = lane & 7;

  const int srow = lane >> 3;
  const int scol = ((lane & 7) ^ srow) << 3;

  const u16* srcs[CPW];
#pragma unroll
  for (int c = 0; c < CPW; ++c) {
    int row = (w * CPW + c) * 8 + srow;
    srcs[c] = (row < BM)
        ? A + (long)(bm * BM + row) * lda + scol
        : B + (long)(bn * BN + (row - BM)) * ldb + scol;
  }

  f32x4 acc[MREP][NREP] = {};

  const int nk = K / BK;
#pragma unroll
  for (int c = 0; c < CPW; ++c)
    gld_lds(srcs[c], &lds[(w * CPW + c) * 512]);

  int p = 0;
  for (int kt = 0; kt < nk; ++kt) {
    if (kt + 1 < nk) {
#pragma unroll
      for (int c = 0; c < CPW; ++c)
        gld_lds(srcs[c] + (kt + 1) * BK, &lds[(p ^ 1) * TILE + (w * CPW + c) * 512]);
      asm volatile("s_waitcnt vmcnt(%0)" :: "i"(CPW) : "memory");
    } else {
      asm volatile("s_waitcnt vmcnt(0)" ::: "memory");
    }
    __builtin_amdgcn_s_barrier();
    asm volatile("" ::: "memory");

    const u16* Alds = &lds[p * TILE];
    const u16* Blds = &lds[p * TILE + BM * BK];
#pragma unroll
    for (int ks = 0; ks < 2; ++ks) {
      const int sl = ((ks * 4 + (lane >> 4)) ^ rx) << 3;
      bf16x8 af[MREP], bfr[NREP];
#pragma unroll
      for (int t = 0; t < MREP; ++t)
        af[t]  = *(const bf16x8*)&Alds[(wr * (BM / 2) + t * 16 + lrow) * BK + sl];
#pragma unroll
      for (int t = 0; t < NREP; ++t)
        bfr[t] = *(const bf16x8*)&Blds[(wc * (BN / WC) + t * 16 + lrow) * BK + sl];
#pragma unroll
      for (int mt = 0; mt < MREP; ++mt)
#pragma unroll
        for (int nt = 0; nt < NREP; ++nt)
          acc[mt][nt] = __builtin_amdgcn_mfma_f32_16x16x32_bf16(af[mt], bfr[nt], acc[mt][nt], 0, 0, 0);
    }

    asm volatile("" ::: "memory");
    __builtin_amdgcn_s_barrier();
    p ^= 1;
  }

  const int row0 = bm * BM + wr * (BM / 2);
  const int col0 = bn * BN + wc * (BN / WC);
  const int rsub = (lane >> 4) << 2;

  if (EPI == 0) {
    u16* C = (u16*)Cv + (long)z * sCz;
#pragma unroll
    for (int mt = 0; mt < MREP; ++mt)
#pragma unroll
      for (int nt = 0; nt < NREP; ++nt)
#pragma unroll
        for (int r = 0; r < 4; ++r) {
          int row = row0 + mt * 16 + rsub + r;
          int col = col0 + nt * 16 + lrow;
          C[(long)row * ldc + col] = bf(acc[mt][nt][r] + bias[col]);
        }
  } else {  // EPI == 4: +bias[row], quantize to i8 with scale 127/4
    signed char* C8 = (signed char*)Cv + (long)z * sCz;
#pragma unroll
    for (int mt = 0; mt < MREP; ++mt)
#pragma unroll
      for (int nt = 0; nt < NREP; ++nt)
#pragma unroll
        for (int r = 0; r < 4; ++r) {
          int row = row0 + mt * 16 + rsub + r;
          int col = col0 + nt * 16 + lrow;
          float v = acc[mt][nt][r] + bias[row];
          float t = fminf(fmaxf(v * 31.75f, -127.f), 127.f);
          C8[(long)row * ldc + col] = (signed char)(int)rintf(t);
        }
  }
}

// ---------------- symmetric sigmoid(QQ^T) GEMM -> u8 P, only bn>=bm --------
// Single-buffered staging (32 KB) -> high occupancy; padded-LDS bounce for
// dense stores. P quantized to u8 (0..127), packed 8B/lane on store.
template <int NB>
__global__ __launch_bounds__(256, 2)
void gemm_sym_sig(const u16* __restrict__ Q, int ldq, long sQz,
                  u8* __restrict__ P, int ldp, long sPz, int K) {
  constexpr int TRI = NB * (NB + 1) / 2;
  constexpr int LSTR = 136;
  __shared__ u16 lds[128 * LSTR];   // staging 16384 u16 | bounce 128x136 u16

  const int tid  = threadIdx.x;
  const int lane = tid & 63;
  const int w    = tid >> 6;
  const int wr   = w >> 1, wc = w & 1;

  const int nwg = (int)gridDim.x;
  const int id  = blockIdx.x;
  const int swz = (id & 7) * (nwg >> 3) + (id >> 3);
  const int z   = swz / TRI;
  int rem = swz % TRI;
  int bm = 0;
  while (rem >= NB - bm) { rem -= NB - bm; ++bm; }
  const int bn = bm + rem;

  const u16* Qz = Q + (long)z * sQz;

  const int lrow = lane & 15;
  const int rx   = lane & 7;
  const int srow = lane >> 3;
  const int scol = ((lane & 7) ^ srow) << 3;

  const u16* srcs[8];
#pragma unroll
  for (int c = 0; c < 8; ++c) {
    int row = (w * 8 + c) * 8 + srow;
    srcs[c] = (row < 128)
        ? Qz + (long)(bm * 128 + row) * ldq + scol
        : Qz + (long)(bn * 128 + (row - 128)) * ldq + scol;
  }

  const u16* Alds = lds;
  const u16* Blds = lds + 128 * 64;

  f32x4 acc[4][4] = {};

  const int nk = K >> 6;
  for (int kt = 0; kt < nk; ++kt) {
#pragma unroll
    for (int c = 0; c < 8; ++c)
      gld_lds(srcs[c] + kt * 64, &lds[(w * 8 + c) * 512]);
    __syncthreads();

#pragma unroll
    for (int ks = 0; ks < 2; ++ks) {
      const int sl = ((ks * 4 + (lane >> 4)) ^ rx) << 3;
      bf16x8 af[4], bfr[4];
#pragma unroll
      for (int t = 0; t < 4; ++t) {
        af[t]  = *(const bf16x8*)&Alds[(wr * 64 + t * 16 + lrow) * 64 + sl];
        bfr[t] = *(const bf16x8*)&Blds[(wc * 64 + t * 16 + lrow) * 64 + sl];
      }
#pragma unroll
      for (int mt = 0; mt < 4; ++mt)
#pragma unroll
        for (int nt = 0; nt < 4; ++nt)
          acc[mt][nt] = __builtin_amdgcn_mfma_f32_16x16x32_bf16(af[mt], bfr[nt], acc[mt][nt], 0, 0, 0);
    }
    __syncthreads();
  }

  u8* Pz = P + (long)z * sPz;
  const int rsub = (lane >> 4) << 2;
  const bool offdiag = (bn != bm);

  // quantize all 64 outputs: u8 value 0..127 held in u16
  u16 sb[4][4][4];
#pragma unroll
  for (int mt = 0; mt < 4; ++mt)
#pragma unroll
    for (int nt = 0; nt < 4; ++nt)
#pragma unroll
      for (int r = 0; r < 4; ++r)
        sb[mt][nt][r] = (u16)(sigmoid_s(acc[mt][nt][r]) * 127.f + 0.5f);

  const int rl = wr * 64 + rsub;
  const int cl = wc * 64 + lrow;
  const int coloff = (lane & 15) * 8;

  // pass 1: normal orientation bounce -> packed u8 row stores (8B/lane)
#pragma unroll
  for (int mt = 0; mt < 4; ++mt)
#pragma unroll
    for (int nt = 0; nt < 4; ++nt)
#pragma unroll
      for (int r = 0; r < 4; ++r)
        lds[(rl + mt * 16 + r) * LSTR + cl + nt * 16] = sb[mt][nt][r];
  __syncthreads();
#pragma unroll
  for (int j = 0; j < 8; ++j) {
    int row = j * 16 + w * 4 + (lane >> 4);
    u16x8 v = *(const u16x8*)&lds[row * LSTR + coloff];
    uint2 pk;
    pk.x = (uint32_t)(v[0] & 0xff) | ((uint32_t)(v[1] & 0xff) << 8) |
           ((uint32_t)(v[2] & 0xff) << 16) | ((uint32_t)(v[3] & 0xff) << 24);
    pk.y = (uint32_t)(v[4] & 0xff) | ((uint32_t)(v[5] & 0xff) << 8) |
           ((uint32_t)(v[6] & 0xff) << 16) | ((uint32_t)(v[7] & 0xff) << 24);
    *(uint2*)&Pz[(long)(bm * 128 + row) * ldp + bn * 128 + coloff] = pk;
  }

  if (offdiag) {
    __syncthreads();
    // pass 2: transposed orientation (4 consecutive rows -> uint2 of u16 vals)
#pragma unroll
    for (int mt = 0; mt < 4; ++mt)
#pragma unroll
      for (int nt = 0; nt < 4; ++nt) {
        uint2 pk;
        pk.x = (uint32_t)sb[mt][nt][0] | ((uint32_t)sb[mt][nt][1] << 16);
        pk.y = (uint32_t)sb[mt][nt][2] | ((uint32_t)sb[mt][nt][3] << 16);
        *(uint2*)&lds[(cl + nt * 16) * LSTR + rl + mt * 16] = pk;
      }
    __syncthreads();
#pragma unroll
    for (int j = 0; j < 8; ++j) {
      int row = j * 16 + w * 4 + (lane >> 4);
      u16x8 v = *(const u16x8*)&lds[row * LSTR + coloff];
      uint2 pk;
      pk.x = (uint32_t)(v[0] & 0xff) | ((uint32_t)(v[1] & 0xff) << 8) |
             ((uint32_t)(v[2] & 0xff) << 16) | ((uint32_t)(v[3] & 0xff) << 24);
      pk.y = (uint32_t)(v[4] & 0xff) | ((uint32_t)(v[5] & 0xff) << 8) |
             ((uint32_t)(v[6] & 0xff) << 16) | ((uint32_t)(v[7] & 0xff) << 24);
      *(uint2*)&Pz[(long)(bn * 128 + row) * ldp + bm * 128 + coloff] = pk;
    }
  }
}

// ---------------- O = (SP*SV) * P_i8 @ vT_i8^T, i8 MFMA, 2-phase dbuf ------
// 128x128 tile, 8 waves (2x4), wave tile 64x32. BK=64 (64 B/row for i8).
// Swizzle key = (row>>1)&3 over 4 16B-slots/row (2-way max per 16-lane phase).
__global__ __launch_bounds__(512, 2)
void gemm_pv_i8(const signed char* __restrict__ A,   // P_i8 [4*4096][4096]
                const signed char* __restrict__ B,   // vT_i8 [512][16384]
                float* __restrict__ C, int K) {      // out [4*4096][512]
  constexpr int NBN = 4, NBM = 32;
  constexpr int TILE = 256 * 64;          // bytes per buffer
  __shared__ signed char lds[2 * TILE];   // 32 KB

  const int tid  = threadIdx.x;
  const int lane = tid & 63;
  const int w    = tid >> 6;              // 0..7
  const int wr   = w >> 2, wc = w & 3;

  const int nwg = (int)gridDim.x;
  const int id  = blockIdx.x;
  const int swz = (id & 7) * (nwg >> 3) + (id >> 3);
  const int bn  = swz % NBN;
  const int t0  = swz / NBN;
  const int bm  = t0 % NBM;
  const int z   = t0 / NBM;

  const signed char* Az = A + (long)z * 4096 * 4096;
  const signed char* Bz = B + (long)z * 4096;
  float* Cz = C + (long)z * 4096 * 512;

  const int lrow = lane & 15;
  const int kq   = ((lane >> 4) ^ ((lrow >> 1) & 3)) << 4;   // read slot byte-off

  // staging: 16 chunks x 1KB (16 rows x 64 B); chunk ci = w*2 + c
  const signed char* srcs[2];
#pragma unroll
  for (int c = 0; c < 2; ++c) {
    int ci = w * 2 + c;
    int r  = ci * 16 + (lane >> 2);            // tile row 0..255 (A | B)
    int sl = (lane & 3) ^ ((r >> 1) & 3);      // pre-swizzled source slot
    srcs[c] = (r < 128)
        ? Az + (long)(bm * 128 + r) * 4096 + sl * 16
        : Bz + (long)(bn * 128 + (r - 128)) * 16384 + sl * 16;
  }

  i32x4 acc[4][2] = {};

  const int nk = K >> 6;   // 64
#pragma unroll
  for (int c = 0; c < 2; ++c)
    gld_lds(srcs[c], &lds[(w * 2 + c) * 1024]);

  int p = 0;
  for (int kt = 0; kt < nk; ++kt) {
    if (kt + 1 < nk) {
#pragma unroll
      for (int c = 0; c < 2; ++c)
        gld_lds(srcs[c] + (kt + 1) * 64, &lds[(p ^ 1) * TILE + (w * 2 + c) * 1024]);
      asm volatile("s_waitcnt vmcnt(2)" ::: "memory");
    } else {
      asm volatile("s_waitcnt vmcnt(0)" ::: "memory");
    }
    __builtin_amdgcn_s_barrier();
    asm volatile("" ::: "memory");

    const signed char* Al = &lds[p * TILE];
    const signed char* Bl = &lds[p * TILE + 128 * 64];
    i32x4 af[4], bfv[2];
#pragma unroll
    for (int mt = 0; mt < 4; ++mt)
      af[mt] = *(const i32x4*)&Al[(wr * 64 + mt * 16 + lrow) * 64 + kq];
#pragma unroll
    for (int nt = 0; nt < 2; ++nt)
      bfv[nt] = *(const i32x4*)&Bl[(wc * 32 + nt * 16 + lrow) * 64 + kq];
#pragma unroll
    for (int mt = 0; mt < 4; ++mt)
#pragma unroll
      for (int nt = 0; nt < 2; ++nt)
        acc[mt][nt] = __builtin_amdgcn_mfma_i32_16x16x64_i8(af[mt], bfv[nt], acc[mt][nt], 0, 0, 0);

    asm volatile("" ::: "memory");
    __builtin_amdgcn_s_barrier();
    p ^= 1;
  }

  // epilogue: scale by SP*SV = (1/127)*(4/127)
  const float SC = 4.0f / 16129.0f;
  const int row0 = bm * 128 + wr * 64;
  const int col0 = bn * 128 + wc * 32;
  const int rsub = (lane >> 4) << 2;
#pragma unroll
  for (int mt = 0; mt < 4; ++mt)
#pragma unroll
    for (int nt = 0; nt < 2; ++nt)
#pragma unroll
      for (int r = 0; r < 4; ++r)
        Cz[(long)(row0 + mt * 16 + rsub + r) * 512 + col0 + nt * 16 + lrow] =
            SC * (float)acc[mt][nt][r];
}

// ---------------- launch ----------------
extern "C" void kernel_launch(void* const* d_in, const int* in_sizes, int n_in,
                              void* d_out, int out_size, void* d_ws, size_t ws_size,
                              hipStream_t stream) {
  const float* x  = (const float*)d_in[0];   // [4,4096,512]
  const float* Wq = (const float*)d_in[1];   // [512,512]
  const float* bq = (const float*)d_in[2];   // [512]
  const float* Wv = (const float*)d_in[3];   // [512,512]
  const float* bv = (const float*)d_in[4];   // [512]
  float* out = (float*)d_out;                // [4,4096,512] f32

  // workspace carve (~110 MB)
  char* wsb = (char*)d_ws;
  u16* xb  = (u16*)wsb;                                   // [16384][512] bf16
  u16* qb  = (u16*)(wsb + 33554432);                      // [16384][512] bf16
  signed char* vT8 = (signed char*)(wsb + 67108864);      // [512][16384] i8
  u16* wqb = (u16*)(wsb + 75497472);                      // [512][512] bf16
  u16* wvb = (u16*)(wsb + 76021760);                      // [512][512] bf16
  u8*  P8  = (u8*)(wsb + 76546048);                       // [4][4096][4096] u8

  conv_kernel<<<8704, 256, 0, stream>>>(x, Wq, Wv, xb, wqb, wvb);

  // q[n][e] = sum_d xb[n][d]*Wq[e][d] + bq[e]  -> bf16
  gemm_nt<0, 128, 128, 4, 4, 128><<<512, 256, 0, stream>>>(xb, 512, 0, wqb, 512, 0,
                                                           qb, 512, 0, bq, 512);
  // vT[e][n] = sum_d Wv[e][d]*xb[n][d] + bv[e] -> i8 (scale 127/4)
  gemm_nt<4, 128, 128, 4, 128, 4><<<512, 256, 0, stream>>>(wvb, 512, 0, xb, 512, 0,
                                                           vT8, 16384, 0, bv, 512);

  // P = round(127*sigmoid(q q^T / sqrt(512))) u8, symmetric dual-store
  gemm_sym_sig<32><<<4 * 528, 256, 0, stream>>>(qb, 512, (long)4096 * 512,
                                                P8, 4096, (long)4096 * 4096, 512);

  // O = (1/127)*(4/127) * P_i8 @ v_i8
  gemm_pv_i8<<<512, 512, 0, stream>>>(P8 ? (const signed char*)P8 : nullptr,
                                      vT8, out, 4096);
}

// Round 9
// 122.740 us; speedup vs baseline: 1.4013x; 1.1653x over previous
//
#include <hip/hip_runtime.h>
#include <hip/hip_bf16.h>
#include <stdint.h>

#define DEV __device__ __forceinline__

typedef unsigned short u16;
typedef unsigned char u8;
typedef __attribute__((ext_vector_type(8))) short bf16x8;        // 8 bf16 MFMA A/B frag
typedef __attribute__((ext_vector_type(4))) float f32x4;         // MFMA C/D frag
typedef __attribute__((ext_vector_type(4))) int i32x4;           // i8 MFMA frag / acc

DEV u16 bf(float v) {
  __hip_bfloat16 h = __float2bfloat16(v);
  union { __hip_bfloat16 h; u16 u; } x; x.h = h;
  return x.u;
}

// sigmoid(v/sqrt(512)) = 1/(1+exp2(v * -log2(e)/sqrt(512)))
DEV float sigmoid_s(float v) {
  float e = __builtin_amdgcn_exp2f(v * -0.0637587143f);
  return __builtin_amdgcn_rcpf(1.0f + e);
}

DEV void gld_lds(const void* g, void* l) {
  __builtin_amdgcn_global_load_lds(
      (const __attribute__((address_space(1))) uint32_t*)g,
      (__attribute__((address_space(3))) uint32_t*)l, 16, 0, 0);
}

// ---------------- f32 -> bf16 conversion (x, Wq, Wv) ----------------
__global__ void conv_kernel(const float* __restrict__ x,
                            const float* __restrict__ Wq,
                            const float* __restrict__ Wv,
                            u16* __restrict__ xb,
                            u16* __restrict__ wqb,
                            u16* __restrict__ wvb) {
  const int NX4 = (16384 * 512) / 4;
  const int NW4 = (512 * 512) / 4;
  int i = blockIdx.x * blockDim.x + threadIdx.x;
  const float4* src; u16* dst; int off;
  if (i < NX4)            { src = (const float4*)x;  dst = xb;  off = i; }
  else if (i < NX4 + NW4) { src = (const float4*)Wq; dst = wqb; off = i - NX4; }
  else                    { src = (const float4*)Wv; dst = wvb; off = i - NX4 - NW4; }
  float4 f = src[off];
  ushort4 o = make_ushort4(bf(f.x), bf(f.y), bf(f.z), bf(f.w));
  ((ushort4*)dst)[off] = o;
}

// ---------------- projection GEMM (bf16 in, i8 out), 2-phase dbuf ----------
// C[m][n] = sum_k A[m][k]*B[n][k].  T1 XCD swizzle; T2 LDS XOR swizzle.
// EPI: 4 = +bias[row] -> i8 | 5 = +bias[col] -> i8   (scale 127/4)
template <int EPI, int BM, int BN, int NW, int NBN, int NBM>
__global__ __launch_bounds__(NW * 64, 2)
void gemm_nt(const u16* __restrict__ A, int lda,
             const u16* __restrict__ B, int ldb,
             signed char* __restrict__ C8, int ldc,
             const float* __restrict__ bias, int K) {
  constexpr int BK   = 64;
  constexpr int WC   = NW / 2;
  constexpr int MREP = BM / 32;
  constexpr int NREP = BN / (16 * WC);
  constexpr int CPW  = (BM + BN) / (8 * NW);
  constexpr int TILE = (BM + BN) * BK;
  __shared__ u16 lds[2 * TILE];

  const int tid  = threadIdx.x;
  const int lane = tid & 63;
  const int w    = tid >> 6;
  const int wr   = w / WC, wc = w % WC;

  const int nwg = (int)gridDim.x;
  const int id  = blockIdx.x;
  const int swz = (id & 7) * (nwg >> 3) + (id >> 3);
  const int bn  = swz % NBN;
  const int bm  = (swz / NBN) % NBM;

  const int lrow = lane & 15;
  const int rx   = lane & 7;
  const int srow = lane >> 3;
  const int scol = ((lane & 7) ^ srow) << 3;

  const u16* srcs[CPW];
#pragma unroll
  for (int c = 0; c < CPW; ++c) {
    int row = (w * CPW + c) * 8 + srow;
    srcs[c] = (row < BM)
        ? A + (long)(bm * BM + row) * lda + scol
        : B + (long)(bn * BN + (row - BM)) * ldb + scol;
  }

  f32x4 acc[MREP][NREP] = {};

  const int nk = K / BK;
#pragma unroll
  for (int c = 0; c < CPW; ++c)
    gld_lds(srcs[c], &lds[(w * CPW + c) * 512]);

  int p = 0;
  for (int kt = 0; kt < nk; ++kt) {
    if (kt + 1 < nk) {
#pragma unroll
      for (int c = 0; c < CPW; ++c)
        gld_lds(srcs[c] + (kt + 1) * BK, &lds[(p ^ 1) * TILE + (w * CPW + c) * 512]);
      asm volatile("s_waitcnt vmcnt(%0)" :: "i"(CPW) : "memory");
    } else {
      asm volatile("s_waitcnt vmcnt(0)" ::: "memory");
    }
    __builtin_amdgcn_s_barrier();
    asm volatile("" ::: "memory");

    const u16* Alds = &lds[p * TILE];
    const u16* Blds = &lds[p * TILE + BM * BK];
#pragma unroll
    for (int ks = 0; ks < 2; ++ks) {
      const int sl = ((ks * 4 + (lane >> 4)) ^ rx) << 3;
      bf16x8 af[MREP], bfr[NREP];
#pragma unroll
      for (int t = 0; t < MREP; ++t)
        af[t]  = *(const bf16x8*)&Alds[(wr * (BM / 2) + t * 16 + lrow) * BK + sl];
#pragma unroll
      for (int t = 0; t < NREP; ++t)
        bfr[t] = *(const bf16x8*)&Blds[(wc * (BN / WC) + t * 16 + lrow) * BK + sl];
#pragma unroll
      for (int mt = 0; mt < MREP; ++mt)
#pragma unroll
        for (int nt = 0; nt < NREP; ++nt)
          acc[mt][nt] = __builtin_amdgcn_mfma_f32_16x16x32_bf16(af[mt], bfr[nt], acc[mt][nt], 0, 0, 0);
    }

    asm volatile("" ::: "memory");
    __builtin_amdgcn_s_barrier();
    p ^= 1;
  }

  const int row0 = bm * BM + wr * (BM / 2);
  const int col0 = bn * BN + wc * (BN / WC);
  const int rsub = (lane >> 4) << 2;

#pragma unroll
  for (int mt = 0; mt < MREP; ++mt)
#pragma unroll
    for (int nt = 0; nt < NREP; ++nt)
#pragma unroll
      for (int r = 0; r < 4; ++r) {
        int row = row0 + mt * 16 + rsub + r;
        int col = col0 + nt * 16 + lrow;
        float v = acc[mt][nt][r] + ((EPI == 4) ? bias[row] : bias[col]);
        float t = fminf(fmaxf(v * 31.75f, -127.f), 127.f);
        C8[(long)row * ldc + col] = (signed char)(int)rintf(t);
      }
}

// ---------------- symmetric sigmoid(QQ^T) i8 GEMM -> u8 P, bn>=bm ----------
// Q_i8 [.][512]; per block 256 rows x 512 B. Staging BK=128 B (32 KB, 4 iters,
// single-buffered). i8 MFMA K=64. Epilogue: dequant (4/127)^2 -> sigmoid -> u8,
// LDS bounce (144 B stride: 16B-aligned b128 reads + 4-bank row offset),
// dual-orientation store for off-diagonal tiles.
template <int NB>
__global__ __launch_bounds__(256, 2)
void gemm_sym_sig_i8(const signed char* __restrict__ Q, long sQz,
                     u8* __restrict__ P, long sPz) {
  constexpr int TRI  = NB * (NB + 1) / 2;
  constexpr int LSTR = 144;                 // bounce byte stride
  __shared__ u8 lds[256 * 128];             // 32 KB staging; bounce overlays 128*144

  const int tid  = threadIdx.x;
  const int lane = tid & 63;
  const int w    = tid >> 6;
  const int wr   = w >> 1, wc = w & 1;

  const int nwg = (int)gridDim.x;
  const int id  = blockIdx.x;
  const int swz = (id & 7) * (nwg >> 3) + (id >> 3);
  const int z   = swz / TRI;
  int rem = swz % TRI;
  int bm = 0;
  while (rem >= NB - bm) { rem -= NB - bm; ++bm; }
  const int bn = bm + rem;

  const signed char* Qz = Q + (long)z * sQz;

  const int lrow = lane & 15;
  const int rx   = lane & 7;
  const int srow = lane >> 3;                     // row within 8-row chunk
  const int scol = ((lane & 7) ^ srow) << 4;      // pre-swizzled 16B slot (of 8)

  const signed char* srcs[8];
#pragma unroll
  for (int c = 0; c < 8; ++c) {
    int row = (w * 8 + c) * 8 + srow;             // 0..255
    srcs[c] = (row < 128)
        ? Qz + (long)(bm * 128 + row) * 512 + scol
        : Qz + (long)(bn * 128 + (row - 128)) * 512 + scol;
  }

  i32x4 acc[4][4] = {};

  for (int kt = 0; kt < 4; ++kt) {                // BK = 128 bytes
#pragma unroll
    for (int c = 0; c < 8; ++c)
      gld_lds(srcs[c] + kt * 128, &lds[(w * 8 + c) * 1024]);
    __syncthreads();

#pragma unroll
    for (int ks = 0; ks < 2; ++ks) {              // two 64B k-slices
      const int sl = ((ks * 4 + (lane >> 4)) ^ rx) << 4;
      i32x4 af[4], bfv[4];
#pragma unroll
      for (int t = 0; t < 4; ++t) {
        af[t]  = *(const i32x4*)&lds[(wr * 64 + t * 16 + lrow) * 128 + sl];
        bfv[t] = *(const i32x4*)&lds[128 * 128 + (wc * 64 + t * 16 + lrow) * 128 + sl];
      }
#pragma unroll
      for (int mt = 0; mt < 4; ++mt)
#pragma unroll
        for (int nt = 0; nt < 4; ++nt)
          acc[mt][nt] = __builtin_amdgcn_mfma_i32_16x16x64_i8(af[mt], bfv[nt], acc[mt][nt], 0, 0, 0);
    }
    __syncthreads();
  }

  u8* Pz = P + (long)z * sPz;
  const int rsub = (lane >> 4) << 2;
  const bool offdiag = (bn != bm);

  // dequant (4/127)^2 -> sigmoid -> u8 0..127
  u8 sb[4][4][4];
#pragma unroll
  for (int mt = 0; mt < 4; ++mt)
#pragma unroll
    for (int nt = 0; nt < 4; ++nt)
#pragma unroll
      for (int r = 0; r < 4; ++r) {
        float v = (float)acc[mt][nt][r] * 9.91941e-4f;
        sb[mt][nt][r] = (u8)(int)(sigmoid_s(v) * 127.f + 0.5f);
      }

  const int rl = wr * 64 + rsub;    // local row base (+mt*16, +r)
  const int cl = wc * 64 + lrow;    // local col base (+nt*16)
  const int coloff = (tid & 7) * 16;
  const int rdrow  = tid >> 3;      // 0..31

  // pass 1: normal orientation bounce -> dense 16B stores
#pragma unroll
  for (int mt = 0; mt < 4; ++mt)
#pragma unroll
    for (int nt = 0; nt < 4; ++nt)
#pragma unroll
      for (int r = 0; r < 4; ++r)
        lds[(rl + mt * 16 + r) * LSTR + cl + nt * 16] = sb[mt][nt][r];
  __syncthreads();
#pragma unroll
  for (int j = 0; j < 4; ++j) {
    int row = j * 32 + rdrow;
    uint4 v = *(const uint4*)&lds[row * LSTR + coloff];
    *(uint4*)&Pz[(long)(bm * 128 + row) * 4096 + bn * 128 + coloff] = v;
  }

  if (offdiag) {
    __syncthreads();   // WAR: pass-1 reads done before overwrite
    // pass 2: transposed; frag's 4 consecutive rows -> 4 bytes -> one u32
#pragma unroll
    for (int mt = 0; mt < 4; ++mt)
#pragma unroll
      for (int nt = 0; nt < 4; ++nt) {
        uint32_t pk = (uint32_t)sb[mt][nt][0] | ((uint32_t)sb[mt][nt][1] << 8) |
                      ((uint32_t)sb[mt][nt][2] << 16) | ((uint32_t)sb[mt][nt][3] << 24);
        *(uint32_t*)&lds[(cl + nt * 16) * LSTR + rl + mt * 16] = pk;
      }
    __syncthreads();
#pragma unroll
    for (int j = 0; j < 4; ++j) {
      int row = j * 32 + rdrow;
      uint4 v = *(const uint4*)&lds[row * LSTR + coloff];
      *(uint4*)&Pz[(long)(bn * 128 + row) * 4096 + bm * 128 + coloff] = v;
    }
  }
}

// ---------------- O = (SP*SV) * P_u8 @ vT_i8^T, i8 MFMA, 2-phase dbuf ------
// 128x128 tile, 4 waves (2x2), wave tile 64x64 (MREP=NREP=4: 8 ds_reads per
// 16 MFMA — 2/3 the LDS traffic of the 8-wave 64x32 arrangement).
__global__ __launch_bounds__(256, 2)
void gemm_pv_i8(const signed char* __restrict__ A,   // P [4*4096][4096] (u8 vals)
                const signed char* __restrict__ B,   // vT_i8 [512][16384]
                float* __restrict__ C, int K) {      // out [4*4096][512]
  constexpr int NBN = 4, NBM = 32;
  constexpr int TILE = 256 * 64;          // bytes per buffer (16 KB)
  __shared__ signed char lds[2 * TILE];   // 32 KB

  const int tid  = threadIdx.x;
  const int lane = tid & 63;
  const int w    = tid >> 6;              // 0..3
  const int wr   = w >> 1, wc = w & 1;

  const int nwg = (int)gridDim.x;
  const int id  = blockIdx.x;
  const int swz = (id & 7) * (nwg >> 3) + (id >> 3);
  const int bn  = swz % NBN;
  const int t0  = swz / NBN;
  const int bm  = t0 % NBM;
  const int z   = t0 / NBM;

  const signed char* Az = A + (long)z * 4096 * 4096;
  const signed char* Bz = B + (long)z * 4096;
  float* Cz = C + (long)z * 4096 * 512;

  const int lrow = lane & 15;
  const int kq   = ((lane >> 4) ^ ((lrow >> 1) & 3)) << 4;   // read slot byte-off

  // staging: 16 chunks x 1KB (16 rows x 64 B); 4 chunks/wave
  const signed char* srcs[4];
#pragma unroll
  for (int c = 0; c < 4; ++c) {
    int ci = w * 4 + c;
    int r  = ci * 16 + (lane >> 2);            // tile row 0..255 (A | B)
    int sl = (lane & 3) ^ ((r >> 1) & 3);      // pre-swizzled source slot
    srcs[c] = (r < 128)
        ? Az + (long)(bm * 128 + r) * 4096 + sl * 16
        : Bz + (long)(bn * 128 + (r - 128)) * 16384 + sl * 16;
  }

  i32x4 acc[4][4] = {};

  const int nk = K >> 6;   // 64
#pragma unroll
  for (int c = 0; c < 4; ++c)
    gld_lds(srcs[c], &lds[(w * 4 + c) * 1024]);

  int p = 0;
  for (int kt = 0; kt < nk; ++kt) {
    if (kt + 1 < nk) {
#pragma unroll
      for (int c = 0; c < 4; ++c)
        gld_lds(srcs[c] + (kt + 1) * 64, &lds[(p ^ 1) * TILE + (w * 4 + c) * 1024]);
      asm volatile("s_waitcnt vmcnt(4)" ::: "memory");
    } else {
      asm volatile("s_waitcnt vmcnt(0)" ::: "memory");
    }
    __builtin_amdgcn_s_barrier();
    asm volatile("" ::: "memory");

    const signed char* Al = &lds[p * TILE];
    const signed char* Bl = &lds[p * TILE + 128 * 64];
    i32x4 af[4], bfv[4];
#pragma unroll
    for (int mt = 0; mt < 4; ++mt)
      af[mt] = *(const i32x4*)&Al[(wr * 64 + mt * 16 + lrow) * 64 + kq];
#pragma unroll
    for (int nt = 0; nt < 4; ++nt)
      bfv[nt] = *(const i32x4*)&Bl[(wc * 64 + nt * 16 + lrow) * 64 + kq];
#pragma unroll
    for (int mt = 0; mt < 4; ++mt)
#pragma unroll
      for (int nt = 0; nt < 4; ++nt)
        acc[mt][nt] = __builtin_amdgcn_mfma_i32_16x16x64_i8(af[mt], bfv[nt], acc[mt][nt], 0, 0, 0);

    asm volatile("" ::: "memory");
    __builtin_amdgcn_s_barrier();
    p ^= 1;
  }

  // epilogue: scale by SP*SV = (1/127)*(4/127)
  const float SC = 4.0f / 16129.0f;
  const int row0 = bm * 128 + wr * 64;
  const int col0 = bn * 128 + wc * 64;
  const int rsub = (lane >> 4) << 2;
#pragma unroll
  for (int mt = 0; mt < 4; ++mt)
#pragma unroll
    for (int nt = 0; nt < 4; ++nt)
#pragma unroll
      for (int r = 0; r < 4; ++r)
        Cz[(long)(row0 + mt * 16 + rsub + r) * 512 + col0 + nt * 16 + lrow] =
            SC * (float)acc[mt][nt][r];
}

// ---------------- launch ----------------
extern "C" void kernel_launch(void* const* d_in, const int* in_sizes, int n_in,
                              void* d_out, int out_size, void* d_ws, size_t ws_size,
                              hipStream_t stream) {
  const float* x  = (const float*)d_in[0];   // [4,4096,512]
  const float* Wq = (const float*)d_in[1];   // [512,512]
  const float* bq = (const float*)d_in[2];   // [512]
  const float* Wv = (const float*)d_in[3];   // [512,512]
  const float* bv = (const float*)d_in[4];   // [512]
  float* out = (float*)d_out;                // [4,4096,512] f32

  // workspace carve (~109 MB)
  char* wsb = (char*)d_ws;
  u16* xb  = (u16*)wsb;                                   // [16384][512] bf16  32 MB
  signed char* qb8 = (signed char*)(wsb + 33554432);      // [16384][512] i8     8 MB
  signed char* vT8 = (signed char*)(wsb + 41943040);      // [512][16384] i8     8 MB
  u16* wqb = (u16*)(wsb + 50331648);                      // [512][512] bf16
  u16* wvb = (u16*)(wsb + 50855936);                      // [512][512] bf16
  u8*  P8  = (u8*)(wsb + 51380224);                       // [4][4096][4096] u8 64 MB

  conv_kernel<<<8704, 256, 0, stream>>>(x, Wq, Wv, xb, wqb, wvb);

  // q[n][e] = sum_d xb[n][d]*Wq[e][d] + bq[e] -> i8 (scale 127/4)
  gemm_nt<5, 128, 128, 4, 4, 128><<<512, 256, 0, stream>>>(xb, 512, wqb, 512,
                                                           qb8, 512, bq, 512);
  // vT[e][n] = sum_d Wv[e][d]*xb[n][d] + bv[e] -> i8 (scale 127/4)
  gemm_nt<4, 128, 128, 4, 128, 4><<<512, 256, 0, stream>>>(wvb, 512, xb, 512,
                                                           vT8, 16384, bv, 512);

  // P = round(127*sigmoid((4/127)^2 * q8 q8^T / sqrt(512))) u8, symmetric
  gemm_sym_sig_i8<32><<<4 * 528, 256, 0, stream>>>(qb8, (long)4096 * 512,
                                                   P8, (long)4096 * 4096);

  // O = (1/127)*(4/127) * P @ v
  gemm_pv_i8<<<512, 256, 0, stream>>>((const signed char*)P8, vT8, out, 4096);
}